// Round 4
// baseline (49304.678 us; speedup 1.0000x reference)
//
#include <hip/hip_runtime.h>
#include <hip/hip_bf16.h>
#include <stdint.h>

// ---------------------------------------------------------------------------
// Persistent-kernel LSTM decoder for MI355X — v4: weight-stationary in VGPRs,
// h-broadcast deduped through L2 (plain loads + per-step agent-acquire fence).
// All kernel stores are write-through (sc0 sc1) => no dirty L2 lines => the
// per-step buffer_inv (fence acquire agent) is safe and makes plain loads
// coherent: first toucher per XCD fills from MALL, rest hit L2.
// superphase s: g1 blocks (0..127): gates1[s] -> h1[s]
//               g2 blocks (128..255): gates2[s-1] -> h2[s-1]
//               fc (fused in g2 blocks 128..139, waves 2-3): frame[s-2] -> out
// ---------------------------------------------------------------------------

#define NSUP 2002

typedef __attribute__((ext_vector_type(8))) short bf16x8;
typedef __attribute__((ext_vector_type(4))) float f32x4;

// ws layout (bytes) — unchanged
#define OFF_WTXT   0ull
#define OFF_WHH1   8388608ull
#define OFF_WPREV  16777216ull
#define OFF_WIH2   17825792ull
#define OFF_WHH2   26214400ull
#define OFF_FCW    34603008ull
#define OFF_BIAS2  34799616ull
#define OFF_PSTYLE 34816000ull
#define OFF_ENC    36913152ull
#define OFF_PREV   141770752ull
#define OFF_H1     207306752ull
#define OFF_H2     207831040ull
#define OFF_FCPART 208355328ull
#define OFF_CNT    208551936ull
#define OFF_STYLET 208553984ull
#define WS_NEED    208717824ull

__device__ __forceinline__ unsigned short f2bf(float f) {
  __hip_bfloat16 b = __float2bfloat16(f);
  return *reinterpret_cast<unsigned short*>(&b);
}
__device__ __forceinline__ float sigm(float x) { return 1.f / (1.f + __expf(-x)); }
__device__ __forceinline__ float tanh_(float x) {
  x = fminf(15.f, fmaxf(-15.f, x));
  float e = __expf(2.f * x);
  return (e - 1.f) / (e + 1.f);
}
__device__ __forceinline__ int origRow(int rp) {
  return ((rp >> 4) & 3) * 1024 + (rp >> 6) * 16 + (rp & 15);
}

#define VMW(n) asm volatile("s_waitcnt vmcnt(" #n ")" ::: "memory")

__device__ __forceinline__ void ldx4(bf16x8& d, const void* p) {
  asm volatile("global_load_dwordx4 %0, %1, off" : "=v"(d) : "v"(p));
}

// ------------------------------- pack kernels -------------------------------
__global__ void k_pack_w1(const float* __restrict__ wih1, const float* __restrict__ whh1,
                          unsigned char* __restrict__ ws) {
  int idx = blockIdx.x * 256 + threadIdx.x;            // 4096*1024
  int rp = idx >> 10, k = idx & 1023;
  int orig = origRow(rp);
  ((unsigned short*)(ws + OFF_WTXT))[idx] = f2bf(wih1[(size_t)orig * 1424 + k]);
  ((unsigned short*)(ws + OFF_WHH1))[idx] = f2bf(whh1[(size_t)orig * 1024 + k]);
}
__global__ void k_pack_w2(const float* __restrict__ wih2, const float* __restrict__ whh2,
                          unsigned char* __restrict__ ws) {
  int idx = blockIdx.x * 256 + threadIdx.x;
  int rp = idx >> 10, k = idx & 1023;
  int orig = origRow(rp);
  ((unsigned short*)(ws + OFF_WIH2))[idx] = f2bf(wih2[(size_t)orig * 1024 + k]);
  ((unsigned short*)(ws + OFF_WHH2))[idx] = f2bf(whh2[(size_t)orig * 1024 + k]);
}
__global__ void k_bias2(const float* __restrict__ bih2, const float* __restrict__ bhh2,
                        unsigned char* __restrict__ ws) {
  int rp = blockIdx.x * 256 + threadIdx.x;
  if (rp >= 4096) return;
  int orig = origRow(rp);
  ((float*)(ws + OFF_BIAS2))[rp] = bih2[orig] + bhh2[orig];
}
__global__ void k_pack_wprev(const float* __restrict__ wih1, unsigned char* __restrict__ ws) {
  int idx = blockIdx.x * 256 + threadIdx.x;            // 4096*128
  int rp = idx >> 7, k = idx & 127;
  int orig = origRow(rp);
  ((unsigned short*)(ws + OFF_WPREV))[idx] =
      (k < 80) ? f2bf(wih1[(size_t)orig * 1424 + 1344 + k]) : (unsigned short)0;
}
__global__ void k_pack_fc(const float* __restrict__ fcw, unsigned char* __restrict__ ws) {
  int idx = blockIdx.x * 256 + threadIdx.x;            // 96*1024
  int r = idx >> 10, k = idx & 1023;
  ((unsigned short*)(ws + OFF_FCW))[idx] =
      (r < 80) ? f2bf(fcw[(size_t)r * 1024 + k]) : (unsigned short)0;
}
__global__ void k_pack_enc(const float* __restrict__ enc, unsigned char* __restrict__ ws) {
  size_t i = (size_t)blockIdx.x * 256 + threadIdx.x;   // 13,107,200 float4's
  float4 v = ((const float4*)enc)[i];
  union { unsigned short u[4]; unsigned long long ll; } z;
  z.u[0] = f2bf(v.x); z.u[1] = f2bf(v.y); z.u[2] = f2bf(v.z); z.u[3] = f2bf(v.w);
  ((unsigned long long*)(ws + OFF_ENC))[i] = z.ll;
}
__global__ void k_styleT(const float* __restrict__ style, float* __restrict__ sT) {
  int idx = blockIdx.x * 256 + threadIdx.x;            // 320*128
  int j = idx >> 7, n = idx & 127;
  sT[idx] = style[n * 320 + j];
}
__global__ void k_pstyle(const float* __restrict__ wih1, const float* __restrict__ bih1,
                         const float* __restrict__ bhh1, const float* __restrict__ sT,
                         unsigned char* __restrict__ ws) {
  int n = threadIdx.x & 127, rsub = threadIdx.x >> 7;
  int rp = blockIdx.x * 2 + rsub;
  int orig = origRow(rp);
  const float* wr = wih1 + (size_t)orig * 1424 + 1024;
  float a0 = 0.f, a1 = 0.f, a2 = 0.f, a3 = 0.f;
  for (int j = 0; j < 320; j += 4) {
    a0 += wr[j + 0] * sT[(j + 0) * 128 + n];
    a1 += wr[j + 1] * sT[(j + 1) * 128 + n];
    a2 += wr[j + 2] * sT[(j + 2) * 128 + n];
    a3 += wr[j + 3] * sT[(j + 3) * 128 + n];
  }
  ((float*)(ws + OFF_PSTYLE))[rp * 128 + n] = (a0 + a1) + (a2 + a3) + bih1[orig] + bhh1[orig];
}
__global__ void k_pack_prev(const float* __restrict__ mel, unsigned char* __restrict__ ws) {
  __shared__ unsigned short pl[64][80];
  int b = blockIdx.y, tt0 = blockIdx.x * 64;
  int tid = threadIdx.x;
  int ttl = tid & 63, mi = tid >> 6;
  for (int m = mi; m < 80; m += 4) {
    int tau = tt0 + ttl;
    if (tau <= 1998) pl[ttl][m] = f2bf(mel[((size_t)b * 80 + m) * 2000 + tau]);
  }
  __syncthreads();
  unsigned short* pv = (unsigned short*)(ws + OFF_PREV);
  for (int idx = tid; idx < 64 * 80; idx += 256) {
    int t2 = idx / 80, m2 = idx % 80;
    int tau = tt0 + t2;
    if (tau <= 1998) pv[((size_t)(tau + 1) * 128 + b) * 128 + m2] = pl[t2][m2];
  }
}

// ------------------------------ persistent kernel ---------------------------
__global__ __launch_bounds__(256, 1) void k_persist(unsigned char* __restrict__ ws,
                                                    float* __restrict__ out,
                                                    const float* __restrict__ fc_b) {
  __shared__ float red[4][64][68];    // 69632 B  cross-wave K reduction
  __shared__ float fcred[2][16][68];  // 8704 B   fc partials (waves 2,3)

  const int tid = threadIdx.x, bid = blockIdx.x;
  const int w = tid >> 6, l = tid & 63;
  const int r15 = l & 15, khi = l >> 4;
  const bool isG1 = bid < 128;
  const int lb = bid & 127, rb = lb >> 1, cg = lb & 1;
  const bool fcB = (!isG1) && (lb < 12);
  const bool fcact = fcB && (w >= 2);     // waves that carry fc loads/MFMA
  const int u6 = lb >> 1;                 // fc row-block (0..5) for fc blocks

  unsigned* cnts = (unsigned*)(ws + OFF_CNT);

  // ---------------- resident A fragments ----------------
  bf16x8 avr[4][17];
  {
    const unsigned char* Wmain =
        ws + (isG1 ? (w < 2 ? OFF_WTXT : OFF_WHH1) : (w < 2 ? OFF_WIH2 : OFF_WHH2)) +
        (size_t)(w & 1) * 1024;  // +512 k-elems
#pragma unroll
    for (int i = 0; i < 4; ++i) {
      const unsigned char* rowp = Wmain + ((size_t)(rb * 64 + 16 * i + r15)) * 2048 + khi * 16;
#pragma unroll
      for (int t = 0; t < 16; ++t) avr[i][t] = *(const bf16x8*)(rowp + t * 64);
      if (isG1)
        avr[i][16] = *(const bf16x8*)(ws + OFF_WPREV +
                                      ((size_t)(rb * 64 + 16 * i + r15)) * 256 + w * 64 + khi * 16);
    }
  }

  // ---------------- per-lane B column offsets ----------------
  size_t encoff[4], hoff[4], prevoff[4];
#pragma unroll
  for (int j = 0; j < 4; ++j) {
    int col = cg * 64 + 16 * j + r15;
    encoff[j] = (size_t)col * 819200 + (size_t)(w & 1) * 1024 + khi * 16;       // w<2 only
    hoff[j]   = (size_t)col * 2048 + (size_t)(w & 1) * 1024 + khi * 16;         // h1/h2 slices
    prevoff[j] = (size_t)col * 256 + w * 64 + khi * 16;
  }
  const unsigned char* fccol = ws + OFF_FCW + ((size_t)(16 * u6 + r15)) * 2048 +
                               (size_t)(w & 1) * 1024 + khi * 16;               // fc waves

  // ---------------- epilogue constants ----------------
  const int ecol = tid & 63, quad = tid >> 6;
  float pstb[4][4];
#pragma unroll
  for (int g = 0; g < 4; ++g)
#pragma unroll
    for (int u = 0; u < 4; ++u) {
      int rloc = 16 * g + quad * 4 + u;
      if (isG1)
        pstb[g][u] = ((const float*)(ws + OFF_PSTYLE))[(size_t)(rb * 64 + rloc) * 128 + cg * 64 + ecol];
      else
        pstb[g][u] = ((const float*)(ws + OFF_BIAS2))[rb * 64 + rloc];
    }
  float fcbr[4];
#pragma unroll
  for (int q = 0; q < 4; ++q) {
    int m = u6 * 16 + quad * 4 + q;
    fcbr[q] = (fcB && m < 80) ? fc_b[m] : 0.f;
  }
  float cst[4] = {0.f, 0.f, 0.f, 0.f};
  const f32x4 zero4 = {0.f, 0.f, 0.f, 0.f};

#pragma unroll 1
  for (int s = 0; s < NSUP; ++s) {
    // Post-barrier acquire: invalidate L1+L2 clean lines so plain loads see
    // this step's MALL-resident h data. No dirty lines exist (all stores are
    // write-through sc0 sc1).
    __builtin_amdgcn_fence(__ATOMIC_ACQUIRE, "agent");

    const bool g1a = isG1 && (s <= 1999);
    const bool g2a = (!isG1) && (s >= 1) && (s <= 2000);
    const bool fca = fcB && (s >= 2) && (s <= 2001);
    const bool g2run = g2a || fca;

    const unsigned char* h1rd = ws + OFF_H1 + (size_t)((s + 1) & 1) * 262144;  // h1[s-1]
    const unsigned char* h2rd = ws + OFF_H2 + (size_t)(s & 1) * 262144;        // h2[s-2]

    if (g1a) {
      // ---------------- gates1 K-loop (T=17) ----------------
      f32x4 acc[4][4];
#pragma unroll
      for (int i = 0; i < 4; ++i)
#pragma unroll
        for (int j = 0; j < 4; ++j) acc[i][j] = zero4;

      const int tp = (s < 399) ? s : 399;
      const unsigned char* bp[4];
      const unsigned char* pp[4];
#pragma unroll
      for (int j = 0; j < 4; ++j) {
        if (w < 2) bp[j] = ws + OFF_ENC + encoff[j] + (size_t)tp * 2048;
        else       bp[j] = h1rd + hoff[j];
        pp[j] = ws + OFF_PREV + (size_t)s * 32768 + prevoff[j];
      }
      bf16x8 bvr[4][4];

      auto ISS = [&](int t) __attribute__((always_inline)) {
        if (t < 16) {
#pragma unroll
          for (int j = 0; j < 4; ++j) { ldx4(bvr[t & 3][j], bp[j]); bp[j] += 64; }
        } else {
#pragma unroll
          for (int j = 0; j < 4; ++j) ldx4(bvr[t & 3][j], pp[j]);
        }
      };

      ISS(0); ISS(1); ISS(2); ISS(3);
#pragma unroll
      for (int t = 0; t < 17; ++t) {
        if (t <= 13) VMW(12);
        else if (t == 14) VMW(8);
        else if (t == 15) VMW(4);
        else VMW(0);
        __builtin_amdgcn_sched_barrier(0);
#pragma unroll
        for (int i = 0; i < 4; ++i)
#pragma unroll
          for (int j = 0; j < 4; ++j)
            acc[i][j] = __builtin_amdgcn_mfma_f32_16x16x32_bf16(avr[i][t], bvr[t & 3][j],
                                                                acc[i][j], 0, 0, 0);
        if (t <= 12) ISS(t + 4);
      }

      // ---------------- epilogue: reduce + LSTM + h1 store ----------------
#pragma unroll
      for (int i = 0; i < 4; ++i)
#pragma unroll
        for (int j = 0; j < 4; ++j)
#pragma unroll
          for (int q = 0; q < 4; ++q)
            red[w][16 * i + khi * 4 + q][16 * j + r15] = acc[i][j][q];
      __syncthreads();
      {
        unsigned hm[4];
#pragma unroll
        for (int u = 0; u < 4; ++u) {
          float gt[4];
#pragma unroll
          for (int g = 0; g < 4; ++g) {
            int row = 16 * g + quad * 4 + u;
            gt[g] = red[0][row][ecol] + red[1][row][ecol] + red[2][row][ecol] +
                    red[3][row][ecol] + pstb[g][u];
          }
          float ci = sigm(gt[0]), cf = sigm(gt[1]), cgt = tanh_(gt[2]), co = sigm(gt[3]);
          cst[u] = cf * cst[u] + ci * cgt;
          hm[u] = f2bf(co * tanh_(cst[u]));
        }
        unsigned long long hv = (unsigned long long)(hm[0] | (hm[1] << 16)) |
                                ((unsigned long long)(hm[2] | (hm[3] << 16)) << 32);
        const void* ha = ws + OFF_H1 + (size_t)(s & 1) * 262144 +
                         (size_t)(cg * 64 + ecol) * 2048 + (size_t)(rb * 16 + quad * 4) * 2;
        asm volatile("global_store_dwordx2 %0, %1, off sc0 sc1" ::"v"(ha), "v"(hv) : "memory");
      }
    } else if (g2run) {
      // ---------------- gates2 (+fc) K-loop (T=16) ----------------
      f32x4 acc[4][4];
      f32x4 facc[4];
#pragma unroll
      for (int i = 0; i < 4; ++i) {
        facc[i] = zero4;
#pragma unroll
        for (int j = 0; j < 4; ++j) acc[i][j] = zero4;
      }
      const unsigned char* bp[4];
#pragma unroll
      for (int j = 0; j < 4; ++j) bp[j] = (w < 2 ? h1rd : h2rd) + hoff[j];
      const unsigned char* fp = fccol;
      bf16x8 bvr[4][4];
      bf16x8 fcav[4];

      auto ISS = [&](int t) __attribute__((always_inline)) {
#pragma unroll
        for (int j = 0; j < 4; ++j) { ldx4(bvr[t & 3][j], bp[j]); bp[j] += 64; }
        if (fcact) { ldx4(fcav[t & 3], fp); fp += 64; }
      };

      ISS(0); ISS(1); ISS(2); ISS(3);
#pragma unroll
      for (int t = 0; t < 16; ++t) {
        if (t <= 12) { if (fcact) VMW(15); else VMW(12); }
        else if (t == 13) { if (fcact) VMW(10); else VMW(8); }
        else if (t == 14) { if (fcact) VMW(5); else VMW(4); }
        else VMW(0);
        __builtin_amdgcn_sched_barrier(0);
        if (g2a) {
#pragma unroll
          for (int i = 0; i < 4; ++i)
#pragma unroll
            for (int j = 0; j < 4; ++j)
              acc[i][j] = __builtin_amdgcn_mfma_f32_16x16x32_bf16(avr[i][t], bvr[t & 3][j],
                                                                  acc[i][j], 0, 0, 0);
        }
        if (fcact && fca) {
#pragma unroll
          for (int j = 0; j < 4; ++j)
            facc[j] = __builtin_amdgcn_mfma_f32_16x16x32_bf16(fcav[t & 3], bvr[t & 3][j],
                                                              facc[j], 0, 0, 0);
        }
        if (t <= 11) ISS(t + 4);
      }

      // ---------------- epilogues ----------------
      if (g2a) {
#pragma unroll
        for (int i = 0; i < 4; ++i)
#pragma unroll
          for (int j = 0; j < 4; ++j)
#pragma unroll
            for (int q = 0; q < 4; ++q)
              red[w][16 * i + khi * 4 + q][16 * j + r15] = acc[i][j][q];
      }
      if (fcact && fca) {
#pragma unroll
        for (int j = 0; j < 4; ++j)
#pragma unroll
          for (int q = 0; q < 4; ++q)
            fcred[w - 2][khi * 4 + q][16 * j + r15] = facc[j][q];
      }
      __syncthreads();
      if (g2a) {
        unsigned hm[4];
#pragma unroll
        for (int u = 0; u < 4; ++u) {
          float gt[4];
#pragma unroll
          for (int g = 0; g < 4; ++g) {
            int row = 16 * g + quad * 4 + u;
            gt[g] = red[0][row][ecol] + red[1][row][ecol] + red[2][row][ecol] +
                    red[3][row][ecol] + pstb[g][u];
          }
          float ci = sigm(gt[0]), cf = sigm(gt[1]), cgt = tanh_(gt[2]), co = sigm(gt[3]);
          cst[u] = cf * cst[u] + ci * cgt;
          hm[u] = f2bf(co * tanh_(cst[u]));
        }
        unsigned long long hv = (unsigned long long)(hm[0] | (hm[1] << 16)) |
                                ((unsigned long long)(hm[2] | (hm[3] << 16)) << 32);
        const void* ha = ws + OFF_H2 + (size_t)((s + 1) & 1) * 262144 +
                         (size_t)(cg * 64 + ecol) * 2048 + (size_t)(rb * 16 + quad * 4) * 2;
        asm volatile("global_store_dwordx2 %0, %1, off sc0 sc1" ::"v"(ha), "v"(hv) : "memory");
      }
      if (fca) {
        const int t0 = s - 2;
#pragma unroll
        for (int q = 0; q < 4; ++q) {
          int m = u6 * 16 + quad * 4 + q;
          float v = fcred[0][quad * 4 + q][ecol] + fcred[1][quad * 4 + q][ecol] + fcbr[q];
          if (m < 80) {
            const float* oa = &out[((size_t)(cg * 64 + ecol) * 80 + m) * 2000 + t0];
            asm volatile("global_store_dword %0, %1, off sc0 sc1" ::"v"(oa), "v"(v) : "memory");
          }
        }
      }
    }

    // ---- global barrier (8 spread counters at MALL, all RELAXED) ----
    asm volatile("s_waitcnt vmcnt(0)" ::: "memory");
    __syncthreads();
    if (tid == 0) {
      __hip_atomic_fetch_add(&cnts[(bid & 7) * 64], 1u, __ATOMIC_RELAXED, __HIP_MEMORY_SCOPE_AGENT);
      unsigned tgt = 256u * (unsigned)(s + 1);
      for (long it = 0; it < 2000000; ++it) {
        unsigned sum = 0;
#pragma unroll
        for (int i2 = 0; i2 < 8; ++i2)
          sum += __hip_atomic_load(&cnts[i2 * 64], __ATOMIC_RELAXED, __HIP_MEMORY_SCOPE_AGENT);
        if (sum >= tgt) break;
        __builtin_amdgcn_s_sleep(1);
      }
    }
    __syncthreads();
  }
}

// --------------------------------- launcher ---------------------------------
extern "C" void kernel_launch(void* const* d_in, const int* in_sizes, int n_in,
                              void* d_out, int out_size, void* d_ws, size_t ws_size,
                              hipStream_t stream) {
  (void)in_sizes; (void)n_in; (void)out_size;
  const float* enc  = (const float*)d_in[0];
  const float* styl = (const float*)d_in[1];
  const float* mel  = (const float*)d_in[2];
  const float* Wih1 = (const float*)d_in[3];
  const float* Whh1 = (const float*)d_in[4];
  const float* bih1 = (const float*)d_in[5];
  const float* bhh1 = (const float*)d_in[6];
  const float* Wih2 = (const float*)d_in[7];
  const float* Whh2 = (const float*)d_in[8];
  const float* bih2 = (const float*)d_in[9];
  const float* bhh2 = (const float*)d_in[10];
  const float* fcw  = (const float*)d_in[11];
  const float* fcb  = (const float*)d_in[12];
  unsigned char* ws = (unsigned char*)d_ws;
  float* out = (float*)d_out;
  if (ws_size < WS_NEED) return;

  hipMemsetAsync(ws + OFF_PREV, 0, (size_t)(OFF_STYLET - OFF_PREV), stream);
  k_pack_w1<<<16384, 256, 0, stream>>>(Wih1, Whh1, ws);
  k_pack_w2<<<16384, 256, 0, stream>>>(Wih2, Whh2, ws);
  k_bias2<<<16, 256, 0, stream>>>(bih2, bhh2, ws);
  k_pack_wprev<<<2048, 256, 0, stream>>>(Wih1, ws);
  k_pack_fc<<<384, 256, 0, stream>>>(fcw, ws);
  k_pack_enc<<<51200, 256, 0, stream>>>(enc, ws);
  k_styleT<<<160, 256, 0, stream>>>(styl, (float*)(ws + OFF_STYLET));
  k_pstyle<<<2048, 256, 0, stream>>>(Wih1, bih1, bhh1, (float*)(ws + OFF_STYLET), ws);
  k_pack_prev<<<dim3(32, 128), 256, 0, stream>>>(mel, ws);
  k_persist<<<256, 256, 0, stream>>>(ws, out, fcb);
}

// Round 5
// 38063.116 us; speedup vs baseline: 1.2953x; 1.2953x over previous
//
#include <hip/hip_runtime.h>
#include <hip/hip_bf16.h>
#include <stdint.h>

// ---------------------------------------------------------------------------
// Persistent-kernel LSTM decoder for MI355X — v5: weight-stationary in VGPRs,
// h-broadcast deduped through L2 with LEADER-ONLY per-XCD invalidation.
// All global stores in k_persist are write-through (sc0 sc1) => no dirty L2
// lines => one buffer_inv per XCD per step (elected leader) makes sc0 loads
// (L1-bypass, L2-cached) coherent: first toucher per XCD fills from MALL,
// remaining ~31 blocks hit L2.
// superphase s: g1 blocks (0..127): gates1[s] -> h1[s]
//               g2 blocks (128..255): gates2[s-1] -> h2[s-1]
//               fc (fused in g2 blocks 128..139, waves 2-3): frame[s-2] -> out
// ---------------------------------------------------------------------------

#define NSUP 2002

typedef __attribute__((ext_vector_type(8))) short bf16x8;
typedef __attribute__((ext_vector_type(4))) float f32x4;

// ws layout (bytes) — unchanged
#define OFF_WTXT   0ull
#define OFF_WHH1   8388608ull
#define OFF_WPREV  16777216ull
#define OFF_WIH2   17825792ull
#define OFF_WHH2   26214400ull
#define OFF_FCW    34603008ull
#define OFF_BIAS2  34799616ull
#define OFF_PSTYLE 34816000ull
#define OFF_ENC    36913152ull
#define OFF_PREV   141770752ull
#define OFF_H1     207306752ull
#define OFF_H2     207831040ull
#define OFF_SYNC   208355328ull   // reuses old fcpart region (zeroed each launch)
#define OFF_STYLET 208553984ull
#define WS_NEED    208717824ull

// sync sub-layout (byte offsets within OFF_SYNC; all 256B-spread)
#define SY_GCNT    0         // gcnt[i]   : i<8, stride 256 B
#define SY_XTK     4096      // xtk[xcd][par] : (xcd*4+par)*256 B
#define SY_XEP     16384     // xep[xcd]  : xcd*256 B

__device__ __forceinline__ unsigned short f2bf(float f) {
  __hip_bfloat16 b = __float2bfloat16(f);
  return *reinterpret_cast<unsigned short*>(&b);
}
__device__ __forceinline__ float sigm(float x) { return 1.f / (1.f + __expf(-x)); }
__device__ __forceinline__ float tanh_(float x) {
  x = fminf(15.f, fmaxf(-15.f, x));
  float e = __expf(2.f * x);
  return (e - 1.f) / (e + 1.f);
}
__device__ __forceinline__ int origRow(int rp) {
  return ((rp >> 4) & 3) * 1024 + (rp >> 6) * 16 + (rp & 15);
}

#define VMW(n) asm volatile("s_waitcnt vmcnt(" #n ")" ::: "memory")

__device__ __forceinline__ void ldx4(bf16x8& d, const void* p) {      // plain: L1+L2
  asm volatile("global_load_dwordx4 %0, %1, off" : "=v"(d) : "v"(p));
}
__device__ __forceinline__ void ldx4_s0(bf16x8& d, const void* p) {   // sc0: L1-bypass, L2-hit
  asm volatile("global_load_dwordx4 %0, %1, off sc0" : "=v"(d) : "v"(p));
}
__device__ __forceinline__ unsigned getXcd() {
  unsigned x;
  asm volatile("s_getreg_b32 %0, hwreg(HW_REG_XCC_ID)" : "=s"(x));
  return x & 7u;
}

// ------------------------------- pack kernels -------------------------------
__global__ void k_pack_w1(const float* __restrict__ wih1, const float* __restrict__ whh1,
                          unsigned char* __restrict__ ws) {
  int idx = blockIdx.x * 256 + threadIdx.x;            // 4096*1024
  int rp = idx >> 10, k = idx & 1023;
  int orig = origRow(rp);
  ((unsigned short*)(ws + OFF_WTXT))[idx] = f2bf(wih1[(size_t)orig * 1424 + k]);
  ((unsigned short*)(ws + OFF_WHH1))[idx] = f2bf(whh1[(size_t)orig * 1024 + k]);
}
__global__ void k_pack_w2(const float* __restrict__ wih2, const float* __restrict__ whh2,
                          unsigned char* __restrict__ ws) {
  int idx = blockIdx.x * 256 + threadIdx.x;
  int rp = idx >> 10, k = idx & 1023;
  int orig = origRow(rp);
  ((unsigned short*)(ws + OFF_WIH2))[idx] = f2bf(wih2[(size_t)orig * 1024 + k]);
  ((unsigned short*)(ws + OFF_WHH2))[idx] = f2bf(whh2[(size_t)orig * 1024 + k]);
}
__global__ void k_bias2(const float* __restrict__ bih2, const float* __restrict__ bhh2,
                        unsigned char* __restrict__ ws) {
  int rp = blockIdx.x * 256 + threadIdx.x;
  if (rp >= 4096) return;
  int orig = origRow(rp);
  ((float*)(ws + OFF_BIAS2))[rp] = bih2[orig] + bhh2[orig];
}
__global__ void k_pack_wprev(const float* __restrict__ wih1, unsigned char* __restrict__ ws) {
  int idx = blockIdx.x * 256 + threadIdx.x;            // 4096*128
  int rp = idx >> 7, k = idx & 127;
  int orig = origRow(rp);
  ((unsigned short*)(ws + OFF_WPREV))[idx] =
      (k < 80) ? f2bf(wih1[(size_t)orig * 1424 + 1344 + k]) : (unsigned short)0;
}
__global__ void k_pack_fc(const float* __restrict__ fcw, unsigned char* __restrict__ ws) {
  int idx = blockIdx.x * 256 + threadIdx.x;            // 96*1024
  int r = idx >> 10, k = idx & 1023;
  ((unsigned short*)(ws + OFF_FCW))[idx] =
      (r < 80) ? f2bf(fcw[(size_t)r * 1024 + k]) : (unsigned short)0;
}
__global__ void k_pack_enc(const float* __restrict__ enc, unsigned char* __restrict__ ws) {
  size_t i = (size_t)blockIdx.x * 256 + threadIdx.x;   // 13,107,200 float4's
  float4 v = ((const float4*)enc)[i];
  union { unsigned short u[4]; unsigned long long ll; } z;
  z.u[0] = f2bf(v.x); z.u[1] = f2bf(v.y); z.u[2] = f2bf(v.z); z.u[3] = f2bf(v.w);
  ((unsigned long long*)(ws + OFF_ENC))[i] = z.ll;
}
__global__ void k_styleT(const float* __restrict__ style, float* __restrict__ sT) {
  int idx = blockIdx.x * 256 + threadIdx.x;            // 320*128
  int j = idx >> 7, n = idx & 127;
  sT[idx] = style[n * 320 + j];
}
__global__ void k_pstyle(const float* __restrict__ wih1, const float* __restrict__ bih1,
                         const float* __restrict__ bhh1, const float* __restrict__ sT,
                         unsigned char* __restrict__ ws) {
  int n = threadIdx.x & 127, rsub = threadIdx.x >> 7;
  int rp = blockIdx.x * 2 + rsub;
  int orig = origRow(rp);
  const float* wr = wih1 + (size_t)orig * 1424 + 1024;
  float a0 = 0.f, a1 = 0.f, a2 = 0.f, a3 = 0.f;
  for (int j = 0; j < 320; j += 4) {
    a0 += wr[j + 0] * sT[(j + 0) * 128 + n];
    a1 += wr[j + 1] * sT[(j + 1) * 128 + n];
    a2 += wr[j + 2] * sT[(j + 2) * 128 + n];
    a3 += wr[j + 3] * sT[(j + 3) * 128 + n];
  }
  ((float*)(ws + OFF_PSTYLE))[rp * 128 + n] = (a0 + a1) + (a2 + a3) + bih1[orig] + bhh1[orig];
}
__global__ void k_pack_prev(const float* __restrict__ mel, unsigned char* __restrict__ ws) {
  __shared__ unsigned short pl[64][80];
  int b = blockIdx.y, tt0 = blockIdx.x * 64;
  int tid = threadIdx.x;
  int ttl = tid & 63, mi = tid >> 6;
  for (int m = mi; m < 80; m += 4) {
    int tau = tt0 + ttl;
    if (tau <= 1998) pl[ttl][m] = f2bf(mel[((size_t)b * 80 + m) * 2000 + tau]);
  }
  __syncthreads();
  unsigned short* pv = (unsigned short*)(ws + OFF_PREV);
  for (int idx = tid; idx < 64 * 80; idx += 256) {
    int t2 = idx / 80, m2 = idx % 80;
    int tau = tt0 + t2;
    if (tau <= 1998) pv[((size_t)(tau + 1) * 128 + b) * 128 + m2] = pl[t2][m2];
  }
}

// ------------------------------ persistent kernel ---------------------------
__global__ __launch_bounds__(256, 1) void k_persist(unsigned char* __restrict__ ws,
                                                    float* __restrict__ out,
                                                    const float* __restrict__ fc_b) {
  __shared__ float red[4][64][68];    // 69632 B  cross-wave K reduction
  __shared__ float fcred[2][16][68];  // 8704 B   fc partials (waves 2,3)

  const int tid = threadIdx.x, bid = blockIdx.x;
  const int w = tid >> 6, l = tid & 63;
  const int r15 = l & 15, khi = l >> 4;
  const bool isG1 = bid < 128;
  const int lb = bid & 127, rb = lb >> 1, cg = lb & 1;
  const bool fcB = (!isG1) && (lb < 12);
  const bool fcact = fcB && (w >= 2);
  const int u6 = lb >> 1;

  unsigned char* sy = ws + OFF_SYNC;
  const unsigned xcd = getXcd();

  // ---------------- resident A fragments ----------------
  bf16x8 avr[4][17];
  {
    const unsigned char* Wmain =
        ws + (isG1 ? (w < 2 ? OFF_WTXT : OFF_WHH1) : (w < 2 ? OFF_WIH2 : OFF_WHH2)) +
        (size_t)(w & 1) * 1024;  // +512 k-elems
#pragma unroll
    for (int i = 0; i < 4; ++i) {
      const unsigned char* rowp = Wmain + ((size_t)(rb * 64 + 16 * i + r15)) * 2048 + khi * 16;
#pragma unroll
      for (int t = 0; t < 16; ++t) avr[i][t] = *(const bf16x8*)(rowp + t * 64);
      if (isG1)
        avr[i][16] = *(const bf16x8*)(ws + OFF_WPREV +
                                      ((size_t)(rb * 64 + 16 * i + r15)) * 256 + w * 64 + khi * 16);
    }
  }

  // ---------------- per-lane B column offsets ----------------
  size_t encoff[4], hoff[4], prevoff[4];
#pragma unroll
  for (int j = 0; j < 4; ++j) {
    int col = cg * 64 + 16 * j + r15;
    encoff[j] = (size_t)col * 819200 + (size_t)(w & 1) * 1024 + khi * 16;       // w<2 only
    hoff[j]   = (size_t)col * 2048 + (size_t)(w & 1) * 1024 + khi * 16;         // h1/h2 slices
    prevoff[j] = (size_t)col * 256 + w * 64 + khi * 16;
  }
  const unsigned char* fccol = ws + OFF_FCW + ((size_t)(16 * u6 + r15)) * 2048 +
                               (size_t)(w & 1) * 1024 + khi * 16;

  // ---------------- epilogue constants ----------------
  const int ecol = tid & 63, quad = tid >> 6;
  float pstb[4][4];
#pragma unroll
  for (int g = 0; g < 4; ++g)
#pragma unroll
    for (int u = 0; u < 4; ++u) {
      int rloc = 16 * g + quad * 4 + u;
      if (isG1)
        pstb[g][u] = ((const float*)(ws + OFF_PSTYLE))[(size_t)(rb * 64 + rloc) * 128 + cg * 64 + ecol];
      else
        pstb[g][u] = ((const float*)(ws + OFF_BIAS2))[rb * 64 + rloc];
    }
  float fcbr[4];
#pragma unroll
  for (int q = 0; q < 4; ++q) {
    int m = u6 * 16 + quad * 4 + q;
    fcbr[q] = (fcB && m < 80) ? fc_b[m] : 0.f;
  }
  float cst[4] = {0.f, 0.f, 0.f, 0.f};
  const f32x4 zero4 = {0.f, 0.f, 0.f, 0.f};

#pragma unroll 1
  for (int s = 0; s < NSUP; ++s) {
    const bool g1a = isG1 && (s <= 1999);
    const bool g2a = (!isG1) && (s >= 1) && (s <= 2000);
    const bool fca = fcB && (s >= 2) && (s <= 2001);
    const bool g2run = g2a || fca;

    const unsigned char* h1rd = ws + OFF_H1 + (size_t)((s + 1) & 1) * 262144;  // h1[s-1]
    const unsigned char* h2rd = ws + OFF_H2 + (size_t)(s & 1) * 262144;        // h2[s-2]

    if (g1a) {
      // ---------------- gates1 K-loop (T=17) ----------------
      f32x4 acc[4][4];
#pragma unroll
      for (int i = 0; i < 4; ++i)
#pragma unroll
        for (int j = 0; j < 4; ++j) acc[i][j] = zero4;

      const int tp = (s < 399) ? s : 399;
      const unsigned char* bp[4];
      const unsigned char* pp[4];
#pragma unroll
      for (int j = 0; j < 4; ++j) {
        if (w < 2) bp[j] = ws + OFF_ENC + encoff[j] + (size_t)tp * 2048;
        else       bp[j] = h1rd + hoff[j];
        pp[j] = ws + OFF_PREV + (size_t)s * 32768 + prevoff[j];
      }
      bf16x8 bvr[4][4];

      auto ISS = [&](int t) __attribute__((always_inline)) {
        if (t < 16) {
          if (w < 2) {
#pragma unroll
            for (int j = 0; j < 4; ++j) { ldx4(bvr[t & 3][j], bp[j]); bp[j] += 64; }
          } else {
#pragma unroll
            for (int j = 0; j < 4; ++j) { ldx4_s0(bvr[t & 3][j], bp[j]); bp[j] += 64; }
          }
        } else {
#pragma unroll
          for (int j = 0; j < 4; ++j) ldx4(bvr[t & 3][j], pp[j]);
        }
      };

      ISS(0); ISS(1); ISS(2); ISS(3);
#pragma unroll
      for (int t = 0; t < 17; ++t) {
        if (t <= 13) VMW(12);
        else if (t == 14) VMW(8);
        else if (t == 15) VMW(4);
        else VMW(0);
        __builtin_amdgcn_sched_barrier(0);
#pragma unroll
        for (int i = 0; i < 4; ++i)
#pragma unroll
          for (int j = 0; j < 4; ++j)
            acc[i][j] = __builtin_amdgcn_mfma_f32_16x16x32_bf16(avr[i][t], bvr[t & 3][j],
                                                                acc[i][j], 0, 0, 0);
        if (t <= 12) ISS(t + 4);
      }

      // ---------------- epilogue: reduce + LSTM + h1 store ----------------
#pragma unroll
      for (int i = 0; i < 4; ++i)
#pragma unroll
        for (int j = 0; j < 4; ++j)
#pragma unroll
          for (int q = 0; q < 4; ++q)
            red[w][16 * i + khi * 4 + q][16 * j + r15] = acc[i][j][q];
      __syncthreads();
      {
        unsigned hm[4];
#pragma unroll
        for (int u = 0; u < 4; ++u) {
          float gt[4];
#pragma unroll
          for (int g = 0; g < 4; ++g) {
            int row = 16 * g + quad * 4 + u;
            gt[g] = red[0][row][ecol] + red[1][row][ecol] + red[2][row][ecol] +
                    red[3][row][ecol] + pstb[g][u];
          }
          float ci = sigm(gt[0]), cf = sigm(gt[1]), cgt = tanh_(gt[2]), co = sigm(gt[3]);
          cst[u] = cf * cst[u] + ci * cgt;
          hm[u] = f2bf(co * tanh_(cst[u]));
        }
        unsigned long long hv = (unsigned long long)(hm[0] | (hm[1] << 16)) |
                                ((unsigned long long)(hm[2] | (hm[3] << 16)) << 32);
        const void* ha = ws + OFF_H1 + (size_t)(s & 1) * 262144 +
                         (size_t)(cg * 64 + ecol) * 2048 + (size_t)(rb * 16 + quad * 4) * 2;
        asm volatile("global_store_dwordx2 %0, %1, off sc0 sc1" ::"v"(ha), "v"(hv) : "memory");
      }
    } else if (g2run) {
      // ---------------- gates2 (+fc) K-loop (T=16) ----------------
      f32x4 acc[4][4];
      f32x4 facc[4];
#pragma unroll
      for (int i = 0; i < 4; ++i) {
        facc[i] = zero4;
#pragma unroll
        for (int j = 0; j < 4; ++j) acc[i][j] = zero4;
      }
      const unsigned char* bp[4];
#pragma unroll
      for (int j = 0; j < 4; ++j) bp[j] = (w < 2 ? h1rd : h2rd) + hoff[j];
      const unsigned char* fp = fccol;
      bf16x8 bvr[4][4];
      bf16x8 fcav[4];

      auto ISS = [&](int t) __attribute__((always_inline)) {
#pragma unroll
        for (int j = 0; j < 4; ++j) { ldx4_s0(bvr[t & 3][j], bp[j]); bp[j] += 64; }
        if (fcact) { ldx4(fcav[t & 3], fp); fp += 64; }
      };

      ISS(0); ISS(1); ISS(2); ISS(3);
#pragma unroll
      for (int t = 0; t < 16; ++t) {
        if (t <= 12) { if (fcact) VMW(15); else VMW(12); }
        else if (t == 13) { if (fcact) VMW(10); else VMW(8); }
        else if (t == 14) { if (fcact) VMW(5); else VMW(4); }
        else VMW(0);
        __builtin_amdgcn_sched_barrier(0);
        if (g2a) {
#pragma unroll
          for (int i = 0; i < 4; ++i)
#pragma unroll
            for (int j = 0; j < 4; ++j)
              acc[i][j] = __builtin_amdgcn_mfma_f32_16x16x32_bf16(avr[i][t], bvr[t & 3][j],
                                                                  acc[i][j], 0, 0, 0);
        }
        if (fcact && fca) {
#pragma unroll
          for (int j = 0; j < 4; ++j)
            facc[j] = __builtin_amdgcn_mfma_f32_16x16x32_bf16(fcav[t & 3], bvr[t & 3][j],
                                                              facc[j], 0, 0, 0);
        }
        if (t <= 11) ISS(t + 4);
      }

      // ---------------- epilogues ----------------
      if (g2a) {
#pragma unroll
        for (int i = 0; i < 4; ++i)
#pragma unroll
          for (int j = 0; j < 4; ++j)
#pragma unroll
            for (int q = 0; q < 4; ++q)
              red[w][16 * i + khi * 4 + q][16 * j + r15] = acc[i][j][q];
      }
      if (fcact && fca) {
#pragma unroll
        for (int j = 0; j < 4; ++j)
#pragma unroll
          for (int q = 0; q < 4; ++q)
            fcred[w - 2][khi * 4 + q][16 * j + r15] = facc[j][q];
      }
      __syncthreads();
      if (g2a) {
        unsigned hm[4];
#pragma unroll
        for (int u = 0; u < 4; ++u) {
          float gt[4];
#pragma unroll
          for (int g = 0; g < 4; ++g) {
            int row = 16 * g + quad * 4 + u;
            gt[g] = red[0][row][ecol] + red[1][row][ecol] + red[2][row][ecol] +
                    red[3][row][ecol] + pstb[g][u];
          }
          float ci = sigm(gt[0]), cf = sigm(gt[1]), cgt = tanh_(gt[2]), co = sigm(gt[3]);
          cst[u] = cf * cst[u] + ci * cgt;
          hm[u] = f2bf(co * tanh_(cst[u]));
        }
        unsigned long long hv = (unsigned long long)(hm[0] | (hm[1] << 16)) |
                                ((unsigned long long)(hm[2] | (hm[3] << 16)) << 32);
        const void* ha = ws + OFF_H2 + (size_t)((s + 1) & 1) * 262144 +
                         (size_t)(cg * 64 + ecol) * 2048 + (size_t)(rb * 16 + quad * 4) * 2;
        asm volatile("global_store_dwordx2 %0, %1, off sc0 sc1" ::"v"(ha), "v"(hv) : "memory");
      }
      if (fca) {
        const int t0 = s - 2;
#pragma unroll
        for (int q = 0; q < 4; ++q) {
          int m = u6 * 16 + quad * 4 + q;
          float v = fcred[0][quad * 4 + q][ecol] + fcred[1][quad * 4 + q][ecol] + fcbr[q];
          if (m < 80) {
            const float* oa = &out[((size_t)(cg * 64 + ecol) * 80 + m) * 2000 + t0];
            asm volatile("global_store_dword %0, %1, off sc0 sc1" ::"v"(oa), "v"(v) : "memory");
          }
        }
      }
    }

    // ---- global barrier + leader-only per-XCD L2 invalidation ----
    asm volatile("s_waitcnt vmcnt(0)" ::: "memory");
    __syncthreads();
    if (tid == 0) {
      // arrive (h stores already drained to MALL)
      __hip_atomic_fetch_add((unsigned*)(sy + SY_GCNT + (size_t)(bid & 7) * 256), 1u,
                             __ATOMIC_RELAXED, __HIP_MEMORY_SCOPE_AGENT);
      // per-XCD leader election (slot s&3; reset 2 steps ahead)
      unsigned* tkp = (unsigned*)(sy + SY_XTK + (size_t)(xcd * 4 + (s & 3)) * 256);
      unsigned ticket = __hip_atomic_fetch_add(tkp, 1u, __ATOMIC_RELAXED, __HIP_MEMORY_SCOPE_AGENT);
      unsigned* xep = (unsigned*)(sy + SY_XEP + (size_t)xcd * 256);
      const unsigned tgt = 256u * (unsigned)(s + 1);
      if (ticket == 0) {
        // leader: wait global arrival
        for (long it = 0; it < 4000000; ++it) {
          unsigned sum = 0;
#pragma unroll
          for (int i2 = 0; i2 < 8; ++i2)
            sum += __hip_atomic_load((unsigned*)(sy + SY_GCNT + (size_t)i2 * 256),
                                     __ATOMIC_RELAXED, __HIP_MEMORY_SCOPE_AGENT);
          if (sum >= tgt) break;
          __builtin_amdgcn_s_sleep(1);
        }
        // one invalidation for this XCD, then publish epoch
        __builtin_amdgcn_fence(__ATOMIC_ACQUIRE, "agent");
        asm volatile("s_waitcnt vmcnt(0)" ::: "memory");
        __hip_atomic_store(xep, (unsigned)(s + 1), __ATOMIC_RELAXED, __HIP_MEMORY_SCOPE_AGENT);
        // reset ticket slot for step s+2
        __hip_atomic_store((unsigned*)(sy + SY_XTK + (size_t)(xcd * 4 + ((s + 2) & 3)) * 256), 0u,
                           __ATOMIC_RELAXED, __HIP_MEMORY_SCOPE_AGENT);
      } else {
        for (long it = 0; it < 4000000; ++it) {
          if (__hip_atomic_load(xep, __ATOMIC_RELAXED, __HIP_MEMORY_SCOPE_AGENT) >= (unsigned)(s + 1))
            break;
          __builtin_amdgcn_s_sleep(1);
        }
      }
    }
    __syncthreads();
  }
}

// --------------------------------- launcher ---------------------------------
extern "C" void kernel_launch(void* const* d_in, const int* in_sizes, int n_in,
                              void* d_out, int out_size, void* d_ws, size_t ws_size,
                              hipStream_t stream) {
  (void)in_sizes; (void)n_in; (void)out_size;
  const float* enc  = (const float*)d_in[0];
  const float* styl = (const float*)d_in[1];
  const float* mel  = (const float*)d_in[2];
  const float* Wih1 = (const float*)d_in[3];
  const float* Whh1 = (const float*)d_in[4];
  const float* bih1 = (const float*)d_in[5];
  const float* bhh1 = (const float*)d_in[6];
  const float* Wih2 = (const float*)d_in[7];
  const float* Whh2 = (const float*)d_in[8];
  const float* bih2 = (const float*)d_in[9];
  const float* bhh2 = (const float*)d_in[10];
  const float* fcw  = (const float*)d_in[11];
  const float* fcb  = (const float*)d_in[12];
  unsigned char* ws = (unsigned char*)d_ws;
  float* out = (float*)d_out;
  if (ws_size < WS_NEED) return;

  hipMemsetAsync(ws + OFF_PREV, 0, (size_t)(OFF_STYLET - OFF_PREV), stream);
  k_pack_w1<<<16384, 256, 0, stream>>>(Wih1, Whh1, ws);
  k_pack_w2<<<16384, 256, 0, stream>>>(Wih2, Whh2, ws);
  k_bias2<<<16, 256, 0, stream>>>(bih2, bhh2, ws);
  k_pack_wprev<<<2048, 256, 0, stream>>>(Wih1, ws);
  k_pack_fc<<<384, 256, 0, stream>>>(fcw, ws);
  k_pack_enc<<<51200, 256, 0, stream>>>(enc, ws);
  k_styleT<<<160, 256, 0, stream>>>(styl, (float*)(ws + OFF_STYLET));
  k_pstyle<<<2048, 256, 0, stream>>>(Wih1, bih1, bhh1, (float*)(ws + OFF_STYLET), ws);
  k_pack_prev<<<dim3(32, 128), 256, 0, stream>>>(mel, ws);
  k_persist<<<256, 256, 0, stream>>>(ws, out, fcb);
}

// Round 6
// 36946.732 us; speedup vs baseline: 1.3345x; 1.0302x over previous
//
#include <hip/hip_runtime.h>
#include <hip/hip_bf16.h>
#include <stdint.h>

// ---------------------------------------------------------------------------
// Persistent-kernel LSTM decoder for MI355X — v6: weight-stationary VGPRs +
// latency-hiding K-schedule. Per wave, the K-slices are reordered so every
// wave starts its step with STATIC sources (enc/prev for g1, resident fcw)
// that are prefetched DURING the barrier poll; the recurrent h-loads (MALL-
// direct sc0 sc1, v3-proven coherence) are ring-pipelined behind 5/4 groups
// of MFMA so their ~400-900ns latency is covered.
// superphase s: g1 blocks (0..127): gates1[s] -> h1[s]
//               g2 blocks (128..255): gates2[s-1] -> h2[s-1]
//               fc (fused in g2 blocks 128..139, all 4 waves): frame[s-2]->out
// ---------------------------------------------------------------------------

#define NSUP 2002

typedef __attribute__((ext_vector_type(8))) short bf16x8;
typedef __attribute__((ext_vector_type(4))) float f32x4;

// ws layout (bytes) — unchanged
#define OFF_WTXT   0ull
#define OFF_WHH1   8388608ull
#define OFF_WPREV  16777216ull
#define OFF_WIH2   17825792ull
#define OFF_WHH2   26214400ull
#define OFF_FCW    34603008ull
#define OFF_BIAS2  34799616ull
#define OFF_PSTYLE 34816000ull
#define OFF_ENC    36913152ull
#define OFF_PREV   141770752ull
#define OFF_H1     207306752ull
#define OFF_H2     207831040ull
#define OFF_SYNC   208355328ull
#define OFF_STYLET 208553984ull
#define WS_NEED    208717824ull

__device__ __forceinline__ unsigned short f2bf(float f) {
  __hip_bfloat16 b = __float2bfloat16(f);
  return *reinterpret_cast<unsigned short*>(&b);
}
__device__ __forceinline__ float sigm(float x) { return 1.f / (1.f + __expf(-x)); }
__device__ __forceinline__ float tanh_(float x) {
  x = fminf(15.f, fmaxf(-15.f, x));
  float e = __expf(2.f * x);
  return (e - 1.f) / (e + 1.f);
}
__device__ __forceinline__ int origRow(int rp) {
  return ((rp >> 4) & 3) * 1024 + (rp >> 6) * 16 + (rp & 15);
}

#define VMW(n) asm volatile("s_waitcnt vmcnt(" #n ")" ::: "memory")

__device__ __forceinline__ void ldx4(bf16x8& d, const void* p) {      // plain: L1+L2
  asm volatile("global_load_dwordx4 %0, %1, off" : "=v"(d) : "v"(p));
}
__device__ __forceinline__ void ldx4c(bf16x8& d, const void* p) {     // MALL-direct
  asm volatile("global_load_dwordx4 %0, %1, off sc0 sc1" : "=v"(d) : "v"(p));
}

// ------------------------------- pack kernels -------------------------------
__global__ void k_pack_w1(const float* __restrict__ wih1, const float* __restrict__ whh1,
                          unsigned char* __restrict__ ws) {
  int idx = blockIdx.x * 256 + threadIdx.x;            // 4096*1024
  int rp = idx >> 10, k = idx & 1023;
  int orig = origRow(rp);
  ((unsigned short*)(ws + OFF_WTXT))[idx] = f2bf(wih1[(size_t)orig * 1424 + k]);
  ((unsigned short*)(ws + OFF_WHH1))[idx] = f2bf(whh1[(size_t)orig * 1024 + k]);
}
__global__ void k_pack_w2(const float* __restrict__ wih2, const float* __restrict__ whh2,
                          unsigned char* __restrict__ ws) {
  int idx = blockIdx.x * 256 + threadIdx.x;
  int rp = idx >> 10, k = idx & 1023;
  int orig = origRow(rp);
  ((unsigned short*)(ws + OFF_WIH2))[idx] = f2bf(wih2[(size_t)orig * 1024 + k]);
  ((unsigned short*)(ws + OFF_WHH2))[idx] = f2bf(whh2[(size_t)orig * 1024 + k]);
}
__global__ void k_bias2(const float* __restrict__ bih2, const float* __restrict__ bhh2,
                        unsigned char* __restrict__ ws) {
  int rp = blockIdx.x * 256 + threadIdx.x;
  if (rp >= 4096) return;
  int orig = origRow(rp);
  ((float*)(ws + OFF_BIAS2))[rp] = bih2[orig] + bhh2[orig];
}
__global__ void k_pack_wprev(const float* __restrict__ wih1, unsigned char* __restrict__ ws) {
  int idx = blockIdx.x * 256 + threadIdx.x;            // 4096*128
  int rp = idx >> 7, k = idx & 127;
  int orig = origRow(rp);
  ((unsigned short*)(ws + OFF_WPREV))[idx] =
      (k < 80) ? f2bf(wih1[(size_t)orig * 1424 + 1344 + k]) : (unsigned short)0;
}
__global__ void k_pack_fc(const float* __restrict__ fcw, unsigned char* __restrict__ ws) {
  int idx = blockIdx.x * 256 + threadIdx.x;            // 96*1024
  int r = idx >> 10, k = idx & 1023;
  ((unsigned short*)(ws + OFF_FCW))[idx] =
      (r < 80) ? f2bf(fcw[(size_t)r * 1024 + k]) : (unsigned short)0;
}
__global__ void k_pack_enc(const float* __restrict__ enc, unsigned char* __restrict__ ws) {
  size_t i = (size_t)blockIdx.x * 256 + threadIdx.x;   // 13,107,200 float4's
  float4 v = ((const float4*)enc)[i];
  union { unsigned short u[4]; unsigned long long ll; } z;
  z.u[0] = f2bf(v.x); z.u[1] = f2bf(v.y); z.u[2] = f2bf(v.z); z.u[3] = f2bf(v.w);
  ((unsigned long long*)(ws + OFF_ENC))[i] = z.ll;
}
__global__ void k_styleT(const float* __restrict__ style, float* __restrict__ sT) {
  int idx = blockIdx.x * 256 + threadIdx.x;            // 320*128
  int j = idx >> 7, n = idx & 127;
  sT[idx] = style[n * 320 + j];
}
__global__ void k_pstyle(const float* __restrict__ wih1, const float* __restrict__ bih1,
                         const float* __restrict__ bhh1, const float* __restrict__ sT,
                         unsigned char* __restrict__ ws) {
  int n = threadIdx.x & 127, rsub = threadIdx.x >> 7;
  int rp = blockIdx.x * 2 + rsub;
  int orig = origRow(rp);
  const float* wr = wih1 + (size_t)orig * 1424 + 1024;
  float a0 = 0.f, a1 = 0.f, a2 = 0.f, a3 = 0.f;
  for (int j = 0; j < 320; j += 4) {
    a0 += wr[j + 0] * sT[(j + 0) * 128 + n];
    a1 += wr[j + 1] * sT[(j + 1) * 128 + n];
    a2 += wr[j + 2] * sT[(j + 2) * 128 + n];
    a3 += wr[j + 3] * sT[(j + 3) * 128 + n];
  }
  ((float*)(ws + OFF_PSTYLE))[rp * 128 + n] = (a0 + a1) + (a2 + a3) + bih1[orig] + bhh1[orig];
}
__global__ void k_pack_prev(const float* __restrict__ mel, unsigned char* __restrict__ ws) {
  __shared__ unsigned short pl[64][80];
  int b = blockIdx.y, tt0 = blockIdx.x * 64;
  int tid = threadIdx.x;
  int ttl = tid & 63, mi = tid >> 6;
  for (int m = mi; m < 80; m += 4) {
    int tau = tt0 + ttl;
    if (tau <= 1998) pl[ttl][m] = f2bf(mel[((size_t)b * 80 + m) * 2000 + tau]);
  }
  __syncthreads();
  unsigned short* pv = (unsigned short*)(ws + OFF_PREV);
  for (int idx = tid; idx < 64 * 80; idx += 256) {
    int t2 = idx / 80, m2 = idx % 80;
    int tau = tt0 + t2;
    if (tau <= 1998) pv[((size_t)(tau + 1) * 128 + b) * 128 + m2] = pl[t2][m2];
  }
}

// ------------------------------ persistent kernel ---------------------------
__global__ __launch_bounds__(256, 1) void k_persist(unsigned char* __restrict__ ws,
                                                    float* __restrict__ out,
                                                    const float* __restrict__ fc_b) {
  __shared__ float red[4][64][68];     // 69632 B  cross-wave K reduction
  __shared__ float fcred[4][16][68];   // 17408 B  fc partials (all 4 waves)

  const int tid = threadIdx.x, bid = blockIdx.x;
  const int w = tid >> 6, l = tid & 63;
  const int r15 = l & 15, khi = l >> 4;
  const bool isG1 = bid < 128;
  const int lb = bid & 127, rb = lb >> 1, cg = lb & 1;
  const bool fcB = (!isG1) && (lb < 12);
  const int u6 = lb >> 1;

  unsigned* cnts = (unsigned*)(ws + OFF_SYNC);

  // ---------------- resident A fragments (new K-slicing) ----------------
  // g1: t 0..7 = Wtxt k[w*256 + t*32 ..] ; t=8 = Wprev k[w*32..] ;
  //     t 9..16 = Whh1 k[w*256 + (t-9)*32 ..]
  // g2: t 0..7 = Wih2 k[w*256..] ; t 8..15 = Whh2 k[w*256..] (t=16 unused)
  bf16x8 avr[4][17];
#pragma unroll
  for (int i = 0; i < 4; ++i) {
    const size_t row = (size_t)(rb * 64 + 16 * i + r15);
    if (isG1) {
      const unsigned char* pa = ws + OFF_WTXT + row * 2048 + w * 512 + khi * 16;
      const unsigned char* ph = ws + OFF_WHH1 + row * 2048 + w * 512 + khi * 16;
#pragma unroll
      for (int t = 0; t < 8; ++t) avr[i][t] = *(const bf16x8*)(pa + t * 64);
      avr[i][8] = *(const bf16x8*)(ws + OFF_WPREV + row * 256 + w * 64 + khi * 16);
#pragma unroll
      for (int t = 0; t < 8; ++t) avr[i][9 + t] = *(const bf16x8*)(ph + t * 64);
    } else {
      const unsigned char* pa = ws + OFF_WIH2 + row * 2048 + w * 512 + khi * 16;
      const unsigned char* ph = ws + OFF_WHH2 + row * 2048 + w * 512 + khi * 16;
#pragma unroll
      for (int t = 0; t < 8; ++t) avr[i][t] = *(const bf16x8*)(pa + t * 64);
#pragma unroll
      for (int t = 0; t < 8; ++t) avr[i][8 + t] = *(const bf16x8*)(ph + t * 64);
      avr[i][16] = avr[i][0];
    }
  }
  // resident fcw fragments (fc blocks, all waves): rows 16*u6.., k[w*256..]
  bf16x8 fcav[8];
  if (fcB) {
    const unsigned char* pf = ws + OFF_FCW + (size_t)(u6 * 16 + r15) * 2048 + w * 512 + khi * 16;
#pragma unroll
    for (int t = 0; t < 8; ++t) fcav[t] = *(const bf16x8*)(pf + t * 64);
  }

  // ---------------- per-lane B column bases ----------------
  size_t encb[4], prevb[4], hb[4];
#pragma unroll
  for (int j = 0; j < 4; ++j) {
    int col = cg * 64 + 16 * j + r15;
    encb[j]  = (size_t)col * 819200 + w * 512 + khi * 16;
    prevb[j] = (size_t)col * 256 + w * 64 + khi * 16;
    hb[j]    = (size_t)col * 2048 + w * 512 + khi * 16;
  }

  const int ecol = tid & 63, quad = tid >> 6;
  float fcbr[4];
#pragma unroll
  for (int q = 0; q < 4; ++q) {
    int m = u6 * 16 + quad * 4 + q;
    fcbr[q] = (fcB && m < 80) ? fc_b[m] : 0.f;
  }
  float cst[4] = {0.f, 0.f, 0.f, 0.f};
  const f32x4 zero4 = {0.f, 0.f, 0.f, 0.f};

  // ---------------- g1 persistent ring state ----------------
  bf16x8 bvr[5][4];
  const unsigned char *ep[4], *pp[4], *hp[4];

  auto setupG1 = [&](int ss) __attribute__((always_inline)) {
    const int tp = (ss < 399) ? ss : 399;
    const unsigned char* h1rd = ws + OFF_H1 + (size_t)((ss + 1) & 1) * 262144;
#pragma unroll
    for (int j = 0; j < 4; ++j) {
      ep[j] = ws + OFF_ENC + encb[j] + (size_t)tp * 2048;
      pp[j] = ws + OFF_PREV + (size_t)ss * 32768 + prevb[j];
      hp[j] = h1rd + hb[j];
    }
  };
  auto issG1 = [&](int t) __attribute__((always_inline)) {
    if (t < 8) {
#pragma unroll
      for (int j = 0; j < 4; ++j) { ldx4(bvr[t % 5][j], ep[j]); ep[j] += 64; }
    } else if (t == 8) {
#pragma unroll
      for (int j = 0; j < 4; ++j) ldx4(bvr[3][j], pp[j]);
    } else {
#pragma unroll
      for (int j = 0; j < 4; ++j) { ldx4c(bvr[t % 5][j], hp[j]); hp[j] += 64; }
    }
  };

  if (isG1) {
    setupG1(0);
#pragma unroll
    for (int pc = 0; pc < 5; ++pc) issG1(pc);
  }

#pragma unroll 1
  for (int s = 0; s < NSUP; ++s) {
    const bool g1a = isG1 && (s <= 1999);
    const bool g2a = (!isG1) && (s >= 1) && (s <= 2000);
    const bool fca = fcB && (s >= 2) && (s <= 2001);
    const bool g2run = g2a || fca;

    if (g1a) {
      // ---------------- gates1 K-loop (T=17, ring-5, statics prefetched) ----
      f32x4 acc[4][4];
#pragma unroll
      for (int i = 0; i < 4; ++i)
#pragma unroll
        for (int j = 0; j < 4; ++j) acc[i][j] = zero4;

#pragma unroll
      for (int t = 0; t < 17; ++t) {
        if (t <= 12) VMW(16);
        else if (t == 13) VMW(12);
        else if (t == 14) VMW(8);
        else if (t == 15) VMW(4);
        else VMW(0);
        __builtin_amdgcn_sched_barrier(0);
#pragma unroll
        for (int i = 0; i < 4; ++i)
#pragma unroll
          for (int j = 0; j < 4; ++j)
            acc[i][j] = __builtin_amdgcn_mfma_f32_16x16x32_bf16(avr[i][t], bvr[t % 5][j],
                                                                acc[i][j], 0, 0, 0);
        if (t + 5 <= 16) issG1(t + 5);
      }

      // ---------------- epilogue: reduce + LSTM + h1 store ----------------
#pragma unroll
      for (int i = 0; i < 4; ++i)
#pragma unroll
        for (int j = 0; j < 4; ++j)
#pragma unroll
          for (int q = 0; q < 4; ++q)
            red[w][16 * i + khi * 4 + q][16 * j + r15] = acc[i][j][q];
      __syncthreads();
      {
        const float* PS = (const float*)(ws + OFF_PSTYLE);
        float pb[4][4];
#pragma unroll
        for (int g = 0; g < 4; ++g)
#pragma unroll
          for (int u = 0; u < 4; ++u)
            pb[g][u] = PS[(size_t)(rb * 64 + 16 * g + quad * 4 + u) * 128 + cg * 64 + ecol];
        unsigned hm[4];
#pragma unroll
        for (int u = 0; u < 4; ++u) {
          float gt[4];
#pragma unroll
          for (int g = 0; g < 4; ++g) {
            int row = 16 * g + quad * 4 + u;
            gt[g] = red[0][row][ecol] + red[1][row][ecol] + red[2][row][ecol] +
                    red[3][row][ecol] + pb[g][u];
          }
          float ci = sigm(gt[0]), cf = sigm(gt[1]), cgt = tanh_(gt[2]), co = sigm(gt[3]);
          cst[u] = cf * cst[u] + ci * cgt;
          hm[u] = f2bf(co * tanh_(cst[u]));
        }
        unsigned long long hv = (unsigned long long)(hm[0] | (hm[1] << 16)) |
                                ((unsigned long long)(hm[2] | (hm[3] << 16)) << 32);
        const void* ha = ws + OFF_H1 + (size_t)(s & 1) * 262144 +
                         (size_t)(cg * 64 + ecol) * 2048 + (size_t)(rb * 16 + quad * 4) * 2;
        asm volatile("global_store_dwordx2 %0, %1, off sc0 sc1" ::"v"(ha), "v"(hv) : "memory");
      }
    } else if (g2run) {
      // ---------------- gates2 (+fc) K-loop (T=16, ring-4) ----------------
      f32x4 acc[4][4];
      f32x4 facc[4];
#pragma unroll
      for (int i = 0; i < 4; ++i) {
        facc[i] = zero4;
#pragma unroll
        for (int j = 0; j < 4; ++j) acc[i][j] = zero4;
      }
      const unsigned char* p1[4];
      const unsigned char* p2[4];
      {
        const unsigned char* h1rd = ws + OFF_H1 + (size_t)((s + 1) & 1) * 262144;
        const unsigned char* h2rd = ws + OFF_H2 + (size_t)(s & 1) * 262144;
#pragma unroll
        for (int j = 0; j < 4; ++j) { p1[j] = h1rd + hb[j]; p2[j] = h2rd + hb[j]; }
      }
      bf16x8 bv2[4][4];
      auto issG2 = [&](int t) __attribute__((always_inline)) {
        if (t < 8) {
#pragma unroll
          for (int j = 0; j < 4; ++j) { ldx4c(bv2[t % 4][j], p1[j]); p1[j] += 64; }
        } else {
#pragma unroll
          for (int j = 0; j < 4; ++j) { ldx4c(bv2[t % 4][j], p2[j]); p2[j] += 64; }
        }
      };
#pragma unroll
      for (int pc = 0; pc < 4; ++pc) issG2(pc);

#pragma unroll
      for (int t = 0; t < 16; ++t) {
        if (t <= 12) VMW(12);
        else if (t == 13) VMW(8);
        else if (t == 14) VMW(4);
        else VMW(0);
        __builtin_amdgcn_sched_barrier(0);
        if (g2a) {
#pragma unroll
          for (int i = 0; i < 4; ++i)
#pragma unroll
            for (int j = 0; j < 4; ++j)
              acc[i][j] = __builtin_amdgcn_mfma_f32_16x16x32_bf16(avr[i][t], bv2[t % 4][j],
                                                                  acc[i][j], 0, 0, 0);
        }
        if (fca && t >= 8) {
#pragma unroll
          for (int j = 0; j < 4; ++j)
            facc[j] = __builtin_amdgcn_mfma_f32_16x16x32_bf16(fcav[t - 8], bv2[t % 4][j],
                                                              facc[j], 0, 0, 0);
        }
        if (t + 4 <= 15) issG2(t + 4);
      }

      // ---------------- epilogues ----------------
      if (g2a) {
#pragma unroll
        for (int i = 0; i < 4; ++i)
#pragma unroll
          for (int j = 0; j < 4; ++j)
#pragma unroll
            for (int q = 0; q < 4; ++q)
              red[w][16 * i + khi * 4 + q][16 * j + r15] = acc[i][j][q];
      }
      if (fca) {
#pragma unroll
        for (int j = 0; j < 4; ++j)
#pragma unroll
          for (int q = 0; q < 4; ++q)
            fcred[w][khi * 4 + q][16 * j + r15] = facc[j][q];
      }
      __syncthreads();
      if (g2a) {
        const float* B2 = (const float*)(ws + OFF_BIAS2);
        float pb[4][4];
#pragma unroll
        for (int g = 0; g < 4; ++g)
#pragma unroll
          for (int u = 0; u < 4; ++u)
            pb[g][u] = B2[rb * 64 + 16 * g + quad * 4 + u];
        unsigned hm[4];
#pragma unroll
        for (int u = 0; u < 4; ++u) {
          float gt[4];
#pragma unroll
          for (int g = 0; g < 4; ++g) {
            int row = 16 * g + quad * 4 + u;
            gt[g] = red[0][row][ecol] + red[1][row][ecol] + red[2][row][ecol] +
                    red[3][row][ecol] + pb[g][u];
          }
          float ci = sigm(gt[0]), cf = sigm(gt[1]), cgt = tanh_(gt[2]), co = sigm(gt[3]);
          cst[u] = cf * cst[u] + ci * cgt;
          hm[u] = f2bf(co * tanh_(cst[u]));
        }
        unsigned long long hv = (unsigned long long)(hm[0] | (hm[1] << 16)) |
                                ((unsigned long long)(hm[2] | (hm[3] << 16)) << 32);
        const void* ha = ws + OFF_H2 + (size_t)((s + 1) & 1) * 262144 +
                         (size_t)(cg * 64 + ecol) * 2048 + (size_t)(rb * 16 + quad * 4) * 2;
        asm volatile("global_store_dwordx2 %0, %1, off sc0 sc1" ::"v"(ha), "v"(hv) : "memory");
      }
      if (fca) {
        const int t0 = s - 2;
#pragma unroll
        for (int q = 0; q < 4; ++q) {
          int m = u6 * 16 + quad * 4 + q;
          float v = fcred[0][quad * 4 + q][ecol] + fcred[1][quad * 4 + q][ecol] +
                    fcred[2][quad * 4 + q][ecol] + fcred[3][quad * 4 + q][ecol] + fcbr[q];
          if (m < 80) out[((size_t)(cg * 64 + ecol) * 80 + m) * 2000 + t0] = v;
        }
      }
    }

    // ---- global barrier (flat, 8 spread counters; g1 prefetch under poll) ----
    asm volatile("s_waitcnt vmcnt(0)" ::: "memory");
    __syncthreads();
    if (tid == 0)
      __hip_atomic_fetch_add(&cnts[(bid & 7) * 64], 1u, __ATOMIC_RELAXED,
                             __HIP_MEMORY_SCOPE_AGENT);
    if (isG1 && (s + 1) <= 1999) {
      setupG1(s + 1);
#pragma unroll
      for (int pc = 0; pc < 5; ++pc) issG1(pc);   // static enc groups — legal pre-release
    }
    if (tid == 0) {
      unsigned tgt = 256u * (unsigned)(s + 1);
      for (long it = 0; it < 4000000; ++it) {
        unsigned sum = 0;
#pragma unroll
        for (int i2 = 0; i2 < 8; ++i2)
          sum += __hip_atomic_load(&cnts[i2 * 64], __ATOMIC_RELAXED, __HIP_MEMORY_SCOPE_AGENT);
        if (sum >= tgt) break;
        __builtin_amdgcn_s_sleep(1);
      }
    }
    __syncthreads();
  }
}

// --------------------------------- launcher ---------------------------------
extern "C" void kernel_launch(void* const* d_in, const int* in_sizes, int n_in,
                              void* d_out, int out_size, void* d_ws, size_t ws_size,
                              hipStream_t stream) {
  (void)in_sizes; (void)n_in; (void)out_size;
  const float* enc  = (const float*)d_in[0];
  const float* styl = (const float*)d_in[1];
  const float* mel  = (const float*)d_in[2];
  const float* Wih1 = (const float*)d_in[3];
  const float* Whh1 = (const float*)d_in[4];
  const float* bih1 = (const float*)d_in[5];
  const float* bhh1 = (const float*)d_in[6];
  const float* Wih2 = (const float*)d_in[7];
  const float* Whh2 = (const float*)d_in[8];
  const float* bih2 = (const float*)d_in[9];
  const float* bhh2 = (const float*)d_in[10];
  const float* fcw  = (const float*)d_in[11];
  const float* fcb  = (const float*)d_in[12];
  unsigned char* ws = (unsigned char*)d_ws;
  float* out = (float*)d_out;
  if (ws_size < WS_NEED) return;

  hipMemsetAsync(ws + OFF_PREV, 0, (size_t)(OFF_STYLET - OFF_PREV), stream);
  k_pack_w1<<<16384, 256, 0, stream>>>(Wih1, Whh1, ws);
  k_pack_w2<<<16384, 256, 0, stream>>>(Wih2, Whh2, ws);
  k_bias2<<<16, 256, 0, stream>>>(bih2, bhh2, ws);
  k_pack_wprev<<<2048, 256, 0, stream>>>(Wih1, ws);
  k_pack_fc<<<384, 256, 0, stream>>>(fcw, ws);
  k_pack_enc<<<51200, 256, 0, stream>>>(enc, ws);
  k_styleT<<<160, 256, 0, stream>>>(styl, (float*)(ws + OFF_STYLET));
  k_pstyle<<<2048, 256, 0, stream>>>(Wih1, bih1, bhh1, (float*)(ws + OFF_STYLET), ws);
  k_pack_prev<<<dim3(32, 128), 256, 0, stream>>>(mel, ws);
  k_persist<<<256, 256, 0, stream>>>(ws, out, fcb);
}

// Round 7
// 33720.770 us; speedup vs baseline: 1.4621x; 1.0957x over previous
//
#include <hip/hip_runtime.h>
#include <hip/hip_bf16.h>
#include <stdint.h>

// ---------------------------------------------------------------------------
// Persistent-kernel LSTM decoder for MI355X — v7: weight-stationary VGPRs,
// AGENT-scope (sc1) h traffic via MALL, split-phase barrier with shadow work.
// Step s:
//   shadow (pre-release): g1 computes enc+prev statics (t0..8);
//                         g2 computes h1[s-2] half (t0..7)   [g2 shifted: it
//                         computes gates2[s-2] so both inputs are >=2 barriers old]
//   wait barrier(s-1)
//   part2: g1 h1[s-1] half (t9..16) -> h1[s];  g2 h2[s-3] half + fc -> h2[s-2], frame[s-3]
// h1 ring=3 slots, h2 ring=2 slots. All h stores/loads sc1 (agent/MALL).
// ---------------------------------------------------------------------------

#define NSUP 2003

typedef __attribute__((ext_vector_type(8))) short bf16x8;
typedef __attribute__((ext_vector_type(4))) float f32x4;

// ws layout (bytes)
#define OFF_WTXT   0ull
#define OFF_WHH1   8388608ull
#define OFF_WPREV  16777216ull
#define OFF_WIH2   17825792ull
#define OFF_WHH2   26214400ull
#define OFF_FCW    34603008ull
#define OFF_BIAS2  34799616ull
#define OFF_PSTYLE 34816000ull
#define OFF_ENC    36913152ull
#define OFF_STYLET 141606912ull   // ENC tail; overwritten later by k_pack_enc
#define OFF_PREV   141770752ull
#define OFF_H1     207306752ull   // 3 slots x 262144
#define OFF_H2     208093184ull   // 2 slots x 262144
#define OFF_SYNC   208617472ull   // 8 counters, 256B stride
#define WS_NEED    208717824ull

__device__ __forceinline__ unsigned short f2bf(float f) {
  __hip_bfloat16 b = __float2bfloat16(f);
  return *reinterpret_cast<unsigned short*>(&b);
}
__device__ __forceinline__ float sigm(float x) { return 1.f / (1.f + __expf(-x)); }
__device__ __forceinline__ float tanh_(float x) {
  x = fminf(15.f, fmaxf(-15.f, x));
  float e = __expf(2.f * x);
  return (e - 1.f) / (e + 1.f);
}
__device__ __forceinline__ int origRow(int rp) {
  return ((rp >> 4) & 3) * 1024 + (rp >> 6) * 16 + (rp & 15);
}

#define VMW(n) asm volatile("s_waitcnt vmcnt(" #n ")" ::: "memory")

__device__ __forceinline__ void ldx4(bf16x8& d, const void* p) {      // plain: L1+L2
  asm volatile("global_load_dwordx4 %0, %1, off" : "=v"(d) : "v"(p));
}
__device__ __forceinline__ void ldx4a(bf16x8& d, const void* p) {     // agent: MALL
  asm volatile("global_load_dwordx4 %0, %1, off sc1" : "=v"(d) : "v"(p));
}

// ------------------------------- pack kernels -------------------------------
__global__ void k_pack_w1(const float* __restrict__ wih1, const float* __restrict__ whh1,
                          unsigned char* __restrict__ ws) {
  int idx = blockIdx.x * 256 + threadIdx.x;            // 4096*1024
  int rp = idx >> 10, k = idx & 1023;
  int orig = origRow(rp);
  ((unsigned short*)(ws + OFF_WTXT))[idx] = f2bf(wih1[(size_t)orig * 1424 + k]);
  ((unsigned short*)(ws + OFF_WHH1))[idx] = f2bf(whh1[(size_t)orig * 1024 + k]);
}
__global__ void k_pack_w2(const float* __restrict__ wih2, const float* __restrict__ whh2,
                          unsigned char* __restrict__ ws) {
  int idx = blockIdx.x * 256 + threadIdx.x;
  int rp = idx >> 10, k = idx & 1023;
  int orig = origRow(rp);
  ((unsigned short*)(ws + OFF_WIH2))[idx] = f2bf(wih2[(size_t)orig * 1024 + k]);
  ((unsigned short*)(ws + OFF_WHH2))[idx] = f2bf(whh2[(size_t)orig * 1024 + k]);
}
__global__ void k_bias2(const float* __restrict__ bih2, const float* __restrict__ bhh2,
                        unsigned char* __restrict__ ws) {
  int rp = blockIdx.x * 256 + threadIdx.x;
  if (rp >= 4096) return;
  int orig = origRow(rp);
  ((float*)(ws + OFF_BIAS2))[rp] = bih2[orig] + bhh2[orig];
}
__global__ void k_pack_wprev(const float* __restrict__ wih1, unsigned char* __restrict__ ws) {
  int idx = blockIdx.x * 256 + threadIdx.x;            // 4096*128
  int rp = idx >> 7, k = idx & 127;
  int orig = origRow(rp);
  ((unsigned short*)(ws + OFF_WPREV))[idx] =
      (k < 80) ? f2bf(wih1[(size_t)orig * 1424 + 1344 + k]) : (unsigned short)0;
}
__global__ void k_pack_fc(const float* __restrict__ fcw, unsigned char* __restrict__ ws) {
  int idx = blockIdx.x * 256 + threadIdx.x;            // 96*1024
  int r = idx >> 10, k = idx & 1023;
  ((unsigned short*)(ws + OFF_FCW))[idx] =
      (r < 80) ? f2bf(fcw[(size_t)r * 1024 + k]) : (unsigned short)0;
}
__global__ void k_pack_enc(const float* __restrict__ enc, unsigned char* __restrict__ ws) {
  size_t i = (size_t)blockIdx.x * 256 + threadIdx.x;   // 13,107,200 float4's
  float4 v = ((const float4*)enc)[i];
  union { unsigned short u[4]; unsigned long long ll; } z;
  z.u[0] = f2bf(v.x); z.u[1] = f2bf(v.y); z.u[2] = f2bf(v.z); z.u[3] = f2bf(v.w);
  ((unsigned long long*)(ws + OFF_ENC))[i] = z.ll;
}
__global__ void k_styleT(const float* __restrict__ style, float* __restrict__ sT) {
  int idx = blockIdx.x * 256 + threadIdx.x;            // 320*128
  int j = idx >> 7, n = idx & 127;
  sT[idx] = style[n * 320 + j];
}
__global__ void k_pstyle(const float* __restrict__ wih1, const float* __restrict__ bih1,
                         const float* __restrict__ bhh1, const float* __restrict__ sT,
                         unsigned char* __restrict__ ws) {
  int n = threadIdx.x & 127, rsub = threadIdx.x >> 7;
  int rp = blockIdx.x * 2 + rsub;
  int orig = origRow(rp);
  const float* wr = wih1 + (size_t)orig * 1424 + 1024;
  float a0 = 0.f, a1 = 0.f, a2 = 0.f, a3 = 0.f;
  for (int j = 0; j < 320; j += 4) {
    a0 += wr[j + 0] * sT[(j + 0) * 128 + n];
    a1 += wr[j + 1] * sT[(j + 1) * 128 + n];
    a2 += wr[j + 2] * sT[(j + 2) * 128 + n];
    a3 += wr[j + 3] * sT[(j + 3) * 128 + n];
  }
  ((float*)(ws + OFF_PSTYLE))[rp * 128 + n] = (a0 + a1) + (a2 + a3) + bih1[orig] + bhh1[orig];
}
__global__ void k_pack_prev(const float* __restrict__ mel, unsigned char* __restrict__ ws) {
  __shared__ unsigned short pl[64][80];
  int b = blockIdx.y, tt0 = blockIdx.x * 64;
  int tid = threadIdx.x;
  int ttl = tid & 63, mi = tid >> 6;
  for (int m = mi; m < 80; m += 4) {
    int tau = tt0 + ttl;
    if (tau <= 1998) pl[ttl][m] = f2bf(mel[((size_t)b * 80 + m) * 2000 + tau]);
  }
  __syncthreads();
  unsigned short* pv = (unsigned short*)(ws + OFF_PREV);
  for (int idx = tid; idx < 64 * 80; idx += 256) {
    int t2 = idx / 80, m2 = idx % 80;
    int tau = tt0 + t2;
    if (tau <= 1998) pv[((size_t)(tau + 1) * 128 + b) * 128 + m2] = pl[t2][m2];
  }
}

// ------------------------------ persistent kernel ---------------------------
__global__ __launch_bounds__(256, 1) void k_persist(unsigned char* __restrict__ ws,
                                                    float* __restrict__ out,
                                                    const float* __restrict__ fc_b) {
  __shared__ float red[4][64][68];     // cross-wave K reduction
  __shared__ float fcred[4][16][68];   // fc partials

  const int tid = threadIdx.x, bid = blockIdx.x;
  const int w = tid >> 6, l = tid & 63;
  const int r15 = l & 15, khi = l >> 4;
  const bool isG1 = bid < 128;
  const int lb = bid & 127, rb = lb >> 1, cg = lb & 1;
  const bool fcB = (!isG1) && (lb < 12);
  const int u6 = lb >> 1;

  unsigned* cnts = (unsigned*)(ws + OFF_SYNC);

  // ---------------- resident A fragments ----------------
  // both: t0..7 = (Wtxt|Wih2) k[w*256+t*32..]; t8..15 = (Whh1|Whh2) k[w*256..]
  // g1 extra: avp = Wprev k[w*32..]
  bf16x8 avr[4][16];
  bf16x8 avp[4];
#pragma unroll
  for (int i = 0; i < 4; ++i) {
    const size_t row = (size_t)(rb * 64 + 16 * i + r15);
    const unsigned char* pa =
        ws + (isG1 ? OFF_WTXT : OFF_WIH2) + row * 2048 + w * 512 + khi * 16;
    const unsigned char* ph =
        ws + (isG1 ? OFF_WHH1 : OFF_WHH2) + row * 2048 + w * 512 + khi * 16;
#pragma unroll
    for (int t = 0; t < 8; ++t) avr[i][t] = *(const bf16x8*)(pa + t * 64);
#pragma unroll
    for (int t = 0; t < 8; ++t) avr[i][8 + t] = *(const bf16x8*)(ph + t * 64);
    if (isG1)
      avp[i] = *(const bf16x8*)(ws + OFF_WPREV + row * 256 + w * 64 + khi * 16);
  }
  bf16x8 fcav[8];
  if (fcB) {
    const unsigned char* pf = ws + OFF_FCW + (size_t)(u6 * 16 + r15) * 2048 + w * 512 + khi * 16;
#pragma unroll
    for (int t = 0; t < 8; ++t) fcav[t] = *(const bf16x8*)(pf + t * 64);
  }

  // ---------------- per-lane B column bases ----------------
  size_t encb[4], prevb[4], hb[4];
#pragma unroll
  for (int j = 0; j < 4; ++j) {
    int col = cg * 64 + 16 * j + r15;
    encb[j]  = (size_t)col * 819200 + w * 512 + khi * 16;
    prevb[j] = (size_t)col * 256 + w * 64 + khi * 16;
    hb[j]    = (size_t)col * 2048 + w * 512 + khi * 16;
  }

  const int ecol = tid & 63, quad = tid >> 6;
  float fcbr[4];
#pragma unroll
  for (int q = 0; q < 4; ++q) {
    int m = u6 * 16 + quad * 4 + q;
    fcbr[q] = (fcB && m < 80) ? fc_b[m] : 0.f;
  }
  float cst[4] = {0.f, 0.f, 0.f, 0.f};
  const f32x4 zero4 = {0.f, 0.f, 0.f, 0.f};

  bf16x8 bvr[4][4];  // ring-4 B staging (both phases)

#pragma unroll 1
  for (int s = 0; s < NSUP; ++s) {
    const bool g1a = isG1 && (s <= 1999);
    const bool g2a = (!isG1) && (s >= 2) && (s <= 2001);   // gates2[s-2]
    const bool fca = fcB && (s >= 3) && (s <= 2002);       // frame[s-3]

    const int m3 = s % 3;
    const unsigned char* h1w  = ws + OFF_H1 + (size_t)m3 * 262144;               // h1[s]
    const unsigned char* h1r1 = ws + OFF_H1 + (size_t)((m3 + 2) % 3) * 262144;   // h1[s-1]
    const unsigned char* h1r2 = ws + OFF_H1 + (size_t)((m3 + 1) % 3) * 262144;   // h1[s-2]
    const unsigned char* h2w  = ws + OFF_H2 + (size_t)(s & 1) * 262144;          // h2[s-2]
    const unsigned char* h2r  = ws + OFF_H2 + (size_t)((s + 1) & 1) * 262144;    // h2[s-3]

    f32x4 acc[4][4];
    f32x4 facc[4];
#pragma unroll
    for (int i = 0; i < 4; ++i) {
      facc[i] = zero4;
#pragma unroll
      for (int j = 0; j < 4; ++j) acc[i][j] = zero4;
    }

    const unsigned char *ep[4], *pp[4], *hp[4], *p2[4];

    // ================= SHADOW ZONE (needs no new barrier) =================
    if (g1a) {
      const int tp = (s < 399) ? s : 399;
#pragma unroll
      for (int j = 0; j < 4; ++j) {
        ep[j] = ws + OFF_ENC + encb[j] + (size_t)tp * 2048;
        pp[j] = ws + OFF_PREV + (size_t)s * 32768 + prevb[j];
        hp[j] = h1r1 + hb[j];
      }
      auto ISSs = [&](int t) __attribute__((always_inline)) {
        if (t < 8) {
#pragma unroll
          for (int j = 0; j < 4; ++j) { ldx4(bvr[t & 3][j], ep[j]); ep[j] += 64; }
        } else {
#pragma unroll
          for (int j = 0; j < 4; ++j) ldx4(bvr[t & 3][j], pp[j]);
        }
      };
      ISSs(0); ISSs(1); ISSs(2); ISSs(3);
#pragma unroll
      for (int t = 0; t < 9; ++t) {
        if (t <= 5) VMW(12);
        else if (t == 6) VMW(8);
        else if (t == 7) VMW(4);
        else VMW(0);
        __builtin_amdgcn_sched_barrier(0);
#pragma unroll
        for (int i = 0; i < 4; ++i)
#pragma unroll
          for (int j = 0; j < 4; ++j)
            acc[i][j] = __builtin_amdgcn_mfma_f32_16x16x32_bf16(
                (t < 8) ? avr[i][t] : avp[i], bvr[t & 3][j], acc[i][j], 0, 0, 0);
        if (t + 4 <= 8) ISSs(t + 4);
      }
    } else if (g2a) {
      const unsigned char* p1[4];
#pragma unroll
      for (int j = 0; j < 4; ++j) p1[j] = h1r2 + hb[j];
      auto ISS1 = [&](int t) __attribute__((always_inline)) {
#pragma unroll
        for (int j = 0; j < 4; ++j) { ldx4a(bvr[t & 3][j], p1[j]); p1[j] += 64; }
      };
      ISS1(0); ISS1(1); ISS1(2); ISS1(3);
#pragma unroll
      for (int t = 0; t < 8; ++t) {
        if (t <= 4) VMW(12);
        else if (t == 5) VMW(8);
        else if (t == 6) VMW(4);
        else VMW(0);
        __builtin_amdgcn_sched_barrier(0);
#pragma unroll
        for (int i = 0; i < 4; ++i)
#pragma unroll
          for (int j = 0; j < 4; ++j)
            acc[i][j] = __builtin_amdgcn_mfma_f32_16x16x32_bf16(avr[i][t], bvr[t & 3][j],
                                                                acc[i][j], 0, 0, 0);
        if (t + 4 <= 7) ISS1(t + 4);
      }
    }
    if (g2a || fca) {
#pragma unroll
      for (int j = 0; j < 4; ++j) p2[j] = h2r + hb[j];
    }

    // ================= WAIT barrier(s-1) =================
    if (s > 0 && tid == 0) {
      const unsigned tgt = 256u * (unsigned)s;
      for (long it = 0; it < 4000000; ++it) {
        unsigned sum = 0;
#pragma unroll
        for (int i2 = 0; i2 < 8; ++i2)
          sum += __hip_atomic_load(&cnts[i2 * 64], __ATOMIC_RELAXED, __HIP_MEMORY_SCOPE_AGENT);
        if (sum >= tgt) break;
        __builtin_amdgcn_s_sleep(8);
      }
    }
    __syncthreads();

    // ================= PART 2 (barrier-dependent) =================
    if (g1a) {
      auto ISSh = [&](int t) __attribute__((always_inline)) {
#pragma unroll
        for (int j = 0; j < 4; ++j) { ldx4a(bvr[t & 3][j], hp[j]); hp[j] += 64; }
      };
      ISSh(0); ISSh(1); ISSh(2); ISSh(3);
#pragma unroll
      for (int t = 0; t < 8; ++t) {
        if (t <= 4) VMW(12);
        else if (t == 5) VMW(8);
        else if (t == 6) VMW(4);
        else VMW(0);
        __builtin_amdgcn_sched_barrier(0);
#pragma unroll
        for (int i = 0; i < 4; ++i)
#pragma unroll
          for (int j = 0; j < 4; ++j)
            acc[i][j] = __builtin_amdgcn_mfma_f32_16x16x32_bf16(avr[i][8 + t], bvr[t & 3][j],
                                                                acc[i][j], 0, 0, 0);
        if (t + 4 <= 7) ISSh(t + 4);
      }
      // epilogue: reduce + LSTM + h1 store (agent scope)
#pragma unroll
      for (int i = 0; i < 4; ++i)
#pragma unroll
        for (int j = 0; j < 4; ++j)
#pragma unroll
          for (int q = 0; q < 4; ++q)
            red[w][16 * i + khi * 4 + q][16 * j + r15] = acc[i][j][q];
      __syncthreads();
      {
        const float* PS = (const float*)(ws + OFF_PSTYLE);
        float pb[4][4];
#pragma unroll
        for (int g = 0; g < 4; ++g)
#pragma unroll
          for (int u = 0; u < 4; ++u)
            pb[g][u] = PS[(size_t)(rb * 64 + 16 * g + quad * 4 + u) * 128 + cg * 64 + ecol];
        unsigned hm[4];
#pragma unroll
        for (int u = 0; u < 4; ++u) {
          float gt[4];
#pragma unroll
          for (int g = 0; g < 4; ++g) {
            int row = 16 * g + quad * 4 + u;
            gt[g] = red[0][row][ecol] + red[1][row][ecol] + red[2][row][ecol] +
                    red[3][row][ecol] + pb[g][u];
          }
          float ci = sigm(gt[0]), cf = sigm(gt[1]), cgt = tanh_(gt[2]), co = sigm(gt[3]);
          cst[u] = cf * cst[u] + ci * cgt;
          hm[u] = f2bf(co * tanh_(cst[u]));
        }
        unsigned long long hv = (unsigned long long)(hm[0] | (hm[1] << 16)) |
                                ((unsigned long long)(hm[2] | (hm[3] << 16)) << 32);
        const void* ha = h1w + (size_t)(cg * 64 + ecol) * 2048 + (size_t)(rb * 16 + quad * 4) * 2;
        asm volatile("global_store_dwordx2 %0, %1, off sc1" ::"v"(ha), "v"(hv) : "memory");
      }
    } else if (g2a || fca) {
      auto ISS2 = [&](int t) __attribute__((always_inline)) {
#pragma unroll
        for (int j = 0; j < 4; ++j) { ldx4a(bvr[t & 3][j], p2[j]); p2[j] += 64; }
      };
      ISS2(0); ISS2(1); ISS2(2); ISS2(3);
#pragma unroll
      for (int t = 0; t < 8; ++t) {
        if (t <= 4) VMW(12);
        else if (t == 5) VMW(8);
        else if (t == 6) VMW(4);
        else VMW(0);
        __builtin_amdgcn_sched_barrier(0);
        if (g2a) {
#pragma unroll
          for (int i = 0; i < 4; ++i)
#pragma unroll
            for (int j = 0; j < 4; ++j)
              acc[i][j] = __builtin_amdgcn_mfma_f32_16x16x32_bf16(avr[i][8 + t], bvr[t & 3][j],
                                                                  acc[i][j], 0, 0, 0);
        }
        if (fca) {
#pragma unroll
          for (int j = 0; j < 4; ++j)
            facc[j] = __builtin_amdgcn_mfma_f32_16x16x32_bf16(fcav[t], bvr[t & 3][j],
                                                              facc[j], 0, 0, 0);
        }
        if (t + 4 <= 7) ISS2(t + 4);
      }
      // epilogues
      if (g2a) {
#pragma unroll
        for (int i = 0; i < 4; ++i)
#pragma unroll
          for (int j = 0; j < 4; ++j)
#pragma unroll
            for (int q = 0; q < 4; ++q)
              red[w][16 * i + khi * 4 + q][16 * j + r15] = acc[i][j][q];
      }
      if (fca) {
#pragma unroll
        for (int j = 0; j < 4; ++j)
#pragma unroll
          for (int q = 0; q < 4; ++q)
            fcred[w][khi * 4 + q][16 * j + r15] = facc[j][q];
      }
      __syncthreads();
      if (g2a) {
        const float* B2 = (const float*)(ws + OFF_BIAS2);
        float pb[4][4];
#pragma unroll
        for (int g = 0; g < 4; ++g)
#pragma unroll
          for (int u = 0; u < 4; ++u)
            pb[g][u] = B2[rb * 64 + 16 * g + quad * 4 + u];
        unsigned hm[4];
#pragma unroll
        for (int u = 0; u < 4; ++u) {
          float gt[4];
#pragma unroll
          for (int g = 0; g < 4; ++g) {
            int row = 16 * g + quad * 4 + u;
            gt[g] = red[0][row][ecol] + red[1][row][ecol] + red[2][row][ecol] +
                    red[3][row][ecol] + pb[g][u];
          }
          float ci = sigm(gt[0]), cf = sigm(gt[1]), cgt = tanh_(gt[2]), co = sigm(gt[3]);
          cst[u] = cf * cst[u] + ci * cgt;
          hm[u] = f2bf(co * tanh_(cst[u]));
        }
        unsigned long long hv = (unsigned long long)(hm[0] | (hm[1] << 16)) |
                                ((unsigned long long)(hm[2] | (hm[3] << 16)) << 32);
        const void* ha = h2w + (size_t)(cg * 64 + ecol) * 2048 + (size_t)(rb * 16 + quad * 4) * 2;
        asm volatile("global_store_dwordx2 %0, %1, off sc1" ::"v"(ha), "v"(hv) : "memory");
      }
      if (fca) {
        const int t0 = s - 3;
#pragma unroll
        for (int q = 0; q < 4; ++q) {
          int m = u6 * 16 + quad * 4 + q;
          float v = fcred[0][quad * 4 + q][ecol] + fcred[1][quad * 4 + q][ecol] +
                    fcred[2][quad * 4 + q][ecol] + fcred[3][quad * 4 + q][ecol] + fcbr[q];
          if (m < 80) out[((size_t)(cg * 64 + ecol) * 80 + m) * 2000 + t0] = v;
        }
      }
    }

    // ================= ARRIVE (stores drained first) =================
    VMW(0);
    __syncthreads();
    if (tid == 0)
      __hip_atomic_fetch_add(&cnts[(bid & 7) * 64], 1u, __ATOMIC_RELAXED,
                             __HIP_MEMORY_SCOPE_AGENT);
  }
}

// --------------------------------- launcher ---------------------------------
extern "C" void kernel_launch(void* const* d_in, const int* in_sizes, int n_in,
                              void* d_out, int out_size, void* d_ws, size_t ws_size,
                              hipStream_t stream) {
  (void)in_sizes; (void)n_in; (void)out_size;
  const float* enc  = (const float*)d_in[0];
  const float* styl = (const float*)d_in[1];
  const float* mel  = (const float*)d_in[2];
  const float* Wih1 = (const float*)d_in[3];
  const float* Whh1 = (const float*)d_in[4];
  const float* bih1 = (const float*)d_in[5];
  const float* bhh1 = (const float*)d_in[6];
  const float* Wih2 = (const float*)d_in[7];
  const float* Whh2 = (const float*)d_in[8];
  const float* bih2 = (const float*)d_in[9];
  const float* bhh2 = (const float*)d_in[10];
  const float* fcw  = (const float*)d_in[11];
  const float* fcb  = (const float*)d_in[12];
  unsigned char* ws = (unsigned char*)d_ws;
  float* out = (float*)d_out;
  if (ws_size < WS_NEED) return;

  hipMemsetAsync(ws + OFF_PREV, 0, (size_t)(WS_NEED - OFF_PREV), stream);
  k_pack_w1<<<16384, 256, 0, stream>>>(Wih1, Whh1, ws);
  k_pack_w2<<<16384, 256, 0, stream>>>(Wih2, Whh2, ws);
  k_bias2<<<16, 256, 0, stream>>>(bih2, bhh2, ws);
  k_pack_wprev<<<2048, 256, 0, stream>>>(Wih1, ws);
  k_pack_fc<<<384, 256, 0, stream>>>(fcw, ws);
  k_styleT<<<160, 256, 0, stream>>>(styl, (float*)(ws + OFF_STYLET));
  k_pstyle<<<2048, 256, 0, stream>>>(Wih1, bih1, bhh1, (float*)(ws + OFF_STYLET), ws);
  k_pack_enc<<<51200, 256, 0, stream>>>(enc, ws);   // overwrites STYLET region (done with it)
  k_pack_prev<<<dim3(32, 128), 256, 0, stream>>>(mel, ws);
  k_persist<<<256, 256, 0, stream>>>(ws, out, fcb);
}